// Round 4
// baseline (219.063 us; speedup 1.0000x reference)
//
#include <hip/hip_runtime.h>
#include <hip/hip_bf16.h>

typedef __bf16 bf16;
typedef __attribute__((ext_vector_type(8))) __bf16 bf16x8;
typedef __attribute__((ext_vector_type(4))) __bf16 bf16x4;
typedef __attribute__((ext_vector_type(4))) float f32x4;
typedef __attribute__((ext_vector_type(4))) unsigned int uint4x;

#if __has_builtin(__builtin_amdgcn_exp2f)
#define EXP2F(x) __builtin_amdgcn_exp2f(x)
#else
#define EXP2F(x) exp2f(x)
#endif

#define AS1 __attribute__((address_space(1)))
#define AS3 __attribute__((address_space(3)))

static __device__ __forceinline__ void async_ld16(const bf16* g, bf16* l) {
  __builtin_amdgcn_global_load_lds((const AS1 void*)g, (AS3 void*)l, 16, 0, 0);
}

// f32 -> bf16 with EXPLICIT round-to-nearest-even bit arithmetic.
// Rationale: rounds 2/3 failed with ~9e-3..1.05e-2 systematic error; the
// pairing math is provably correct (pinned by m89 C/D map + round-0 pass),
// so the suspect is the packed convert v_cvt_pk_bf16_f32 rounding (RTZ bias
// ~2^-9 on P while l stays fp32-exact -> O biased low ~1e-3 rel -> ~9e-3
// absmax through fc). Integer RNE cannot be fused into a truncating cvt_pk.
// Valid for positive finite inputs (exp2 output); no NaN handling needed.
static __device__ __forceinline__ unsigned bf16rne(float x) {
  unsigned u = __float_as_uint(x);
  return (u + 0x7fffu + ((u >> 16) & 1u)) >> 16;
}
static __device__ __forceinline__ unsigned pack2(float a, float b) {
  return bf16rne(a) | (bf16rne(b) << 16);
}

// ---------------- fused fp32 -> bf16 conversion (x, qkv_w, fc_w) ----------
__global__ void cvt3_kernel(const float* __restrict__ x, const float* __restrict__ qw,
                            const float* __restrict__ fw, bf16* __restrict__ xb,
                            bf16* __restrict__ qwb, bf16* __restrict__ fwb) {
  int b = blockIdx.x;
  const float* src;
  bf16* dst;
  int i;
  if (b < 4096) { src = x; dst = xb; i = b * 256 + threadIdx.x; }
  else if (b < 7168) { src = qw; dst = qwb; i = (b - 4096) * 256 + threadIdx.x; }
  else { src = fw; dst = fwb; i = (b - 7168) * 256 + threadIdx.x; }
  f32x4 v = *(const f32x4*)(src + (size_t)i * 4);
  bf16x4 o;
  o[0] = (bf16)v[0]; o[1] = (bf16)v[1]; o[2] = (bf16)v[2]; o[3] = (bf16)v[3];
  *(bf16x4*)(dst + (size_t)i * 4) = o;
}

// ---------------- BT-GEMM: C[M,N] = A[M,K] @ B[N,K]^T ----------------
// MODE 0 epilogue: bias + head_mask; Q -> [nh][s][d] (x log2(e)/8);
//   K -> fragment-major Kf with the LANE-LOCAL-P permutation baked in:
//     key slot g (within 128-key tile) sits at QK^T C-tile ct = 2*(g>>5)+((g>>2)&1),
//     tile row i = ((g>>3)&3)*4 + (g&3). Then score for key g lands at
//     lane-quad (g>>3)&3, reg g&3 -> the PV A-fragment needs NO cross-lane
//     exchange at all (see flash_kernel).
//   V -> natural fragment-major Vf (B k-slot (quad,e) <-> key kk*32+quad*8+e).
// MODE 1: fp32 out = acc + bias.
template <int MODE>
__global__ __launch_bounds__(256, 2) void gemm_bt_kernel(
    const bf16* __restrict__ A, const bf16* __restrict__ Bw,
    const float* __restrict__ bias, const float* __restrict__ hm,
    bf16* __restrict__ Qp, bf16* __restrict__ Kp, bf16* __restrict__ Vp,
    float* __restrict__ outF, int Ncols, int Kdim, int rowBlkCount) {
  __shared__ bf16 As[128 * 32];
  __shared__ bf16 Bs[128 * 32];
  const int t = threadIdx.x, lane = t & 63, w = t >> 6;
  const int wr = w >> 1, wc = w & 1;
  const int j = lane & 15, quad = lane >> 4;
  const int rowBlk = blockIdx.x % rowBlkCount;
  const int colBlk = blockIdx.x / rowBlkCount;
  const int rowBase = rowBlk * 128, colBase = colBlk * 128;

  f32x4 acc[4][4];
  const f32x4 z4 = {0.f, 0.f, 0.f, 0.f};
#pragma unroll
  for (int i = 0; i < 4; ++i)
#pragma unroll
    for (int jj = 0; jj < 4; ++jj) acc[i][jj] = z4;

  const int f0 = t * 8;
  const int f1 = f0 + 2048;
  const int r0 = f0 >> 5, c0 = f0 & 31;
  const int r1 = f1 >> 5, c1 = f1 & 31;

  for (int k0 = 0; k0 < Kdim; k0 += 32) {
    async_ld16(A + (size_t)(rowBase + r0) * Kdim + k0 + c0, &As[f0]);
    async_ld16(A + (size_t)(rowBase + r1) * Kdim + k0 + c1, &As[f1]);
    async_ld16(Bw + (size_t)(colBase + r0) * Kdim + k0 + c0, &Bs[f0]);
    async_ld16(Bw + (size_t)(colBase + r1) * Kdim + k0 + c1, &Bs[f1]);
    __syncthreads();
    bf16x8 af[4], bfr[4];
#pragma unroll
    for (int i = 0; i < 4; ++i)
      af[i] = *(const bf16x8*)&As[(wr * 64 + i * 16 + j) * 32 + quad * 8];
#pragma unroll
    for (int jj = 0; jj < 4; ++jj)
      bfr[jj] = *(const bf16x8*)&Bs[(wc * 64 + jj * 16 + j) * 32 + quad * 8];
#pragma unroll
    for (int i = 0; i < 4; ++i)
#pragma unroll
      for (int jj = 0; jj < 4; ++jj)
        acc[i][jj] = __builtin_amdgcn_mfma_f32_16x16x32_bf16(af[i], bfr[jj], acc[i][jj], 0, 0, 0);
    __syncthreads();
  }

  if (MODE == 0) {
#pragma unroll
    for (int jj = 0; jj < 4; ++jj) {
      int col = colBase + wc * 64 + jj * 16 + j;
      int hh = col / 192;
      int rem = col - hh * 192;
      int mm = rem >> 6;   // wave-uniform (16-col runs never cross a 64 boundary)
      int dd = rem & 63;
      float hmv = hm[hh];
      float bv = bias[col];
      float sc = (mm == 0) ? hmv * 0.18033688011112042f : hmv;  // log2(e)/8 folded into Q
#pragma unroll
      for (int i = 0; i < 4; ++i) {
#pragma unroll
        for (int r = 0; r < 4; ++r) {
          int row = rowBase + wr * 64 + i * 16 + quad * 4 + r;
          int n = row >> 11, ss = row & 2047;
          size_t nh = (size_t)(n * 16 + hh);
          float val = (acc[i][jj][r] + bv) * sc;
          if (mm == 0) {
            Qp[nh * 131072 + ss * 64 + dd] = (bf16)val;
          } else if (mm == 1) {
            // lane-local-P Kf: g = ss&127, T = ss>>7,
            // ct = 2*((g>>5)&3) + ((g>>2)&1), i = ((g>>3)&3)*4 + (g&3)
            size_t idx = nh * 131072 + (size_t)(ss >> 7) * 8192 +
                         (size_t)(2 * ((ss >> 5) & 3) + ((ss >> 2) & 1)) * 1024 +
                         (dd >> 5) * 512 + ((dd >> 3) & 3) * 128 +
                         (((ss >> 3) & 3) * 4 + (ss & 3)) * 8 + (dd & 7);
            Kp[idx] = (bf16)val;
          } else {
            // natural fragment-major V: tile (ss>>7), block (kk=(ss>>5)&3, dt=dd>>4),
            // within block quad=(ss>>3)&3, j=dd&15, elem=ss&7
            size_t idx = nh * 131072 + (size_t)(ss >> 7) * 8192 +
                         (((ss >> 5) & 3) * 4 + (dd >> 4)) * 512 +
                         ((ss >> 3) & 3) * 128 + (dd & 15) * 8 + (ss & 7);
            Vp[idx] = (bf16)val;
          }
        }
      }
    }
  } else {
#pragma unroll
    for (int jj = 0; jj < 4; ++jj) {
      int col = colBase + wc * 64 + jj * 16 + j;
      float bv = bias[col];
#pragma unroll
      for (int i = 0; i < 4; ++i)
#pragma unroll
        for (int r = 0; r < 4; ++r) {
          int row = rowBase + wr * 64 + i * 16 + quad * 4 + r;
          outF[(size_t)row * Ncols + col] = acc[i][jj][r] + bv;
        }
    }
  }
}

// ---------------- Flash attention: swapped QK^T, LANE-LOCAL in-register P ---
// grid = 1024: b = qt*64 + nh*2 + ck. Block = 128 q-rows (4 waves x 32).
// Swapped QK^T: s = mfma(K, Q) -> C[col = q = lane&15][row = tile-row].
// Kf bakes the permutation so that tile ct row i holds key
// g = (ct>>1)*32 + quad*8 + (ct&1)*4 + (i&3)  (quad = i>>2):
//   => lane (quad,j) register s[ct][r] = P[q=j][g = (ct>>1)*32 + quad*8 + (ct&1)*4 + r]
//   => PV A-fragment (lane (quad,j) elem e needs key kk*32+quad*8+e) is
//      PURELY LANE-LOCAL: pa = {pack(s[2kk][0..1]), pack(s[2kk][2..3]),
//                               pack(s[2kk+1][0..1]), pack(s[2kk+1][2..3])}.
// No permlane/bpermute/LDS for P; softmax row-sum is lane-local per 32-key
// stripe, folded across quads with 2 shfl_xor at the END.
// P->bf16 via EXPLICIT RNE bit math (see bf16rne) -- not cvt_pk.
// exp2 + pack fused into the ct-loop: cross-iteration P state = 32 dwords.
// LDS 32768 B => 4 blocks/CU, grid 1024 = one resident pass over 256 CUs.
// Fixed max m=0 (scores *log2e/8 baked into Q); l fp32 from unquantized exp2.
__global__ __launch_bounds__(256, 4) void flash_kernel(const bf16* __restrict__ Qp,
                                                       const bf16* __restrict__ Kf,
                                                       const bf16* __restrict__ Vf,
                                                       float* __restrict__ O0,
                                                       float* __restrict__ O1,
                                                       float* __restrict__ Lp) {
  __shared__ bf16 Ks[8192];
  __shared__ bf16 Vs[8192];
  const int t = threadIdx.x, lane = t & 63, w = t >> 6;
  const int j = lane & 15, quad = lane >> 4;
  const int g = blockIdx.x & 63;
  const int qt = blockIdx.x >> 6;   // [0,16)
  const int nh = g >> 1, ck = g & 1;
  const int q0 = qt * 128 + w * 32;
  const bf16* Qb = Qp + (size_t)nh * 131072;
  const bf16* Kc = Kf + (size_t)nh * 131072 + ck * 65536;
  const bf16* Vc = Vf + (size_t)nh * 131072 + ck * 65536;

  bf16x8 qf[2][2];
#pragma unroll
  for (int rt = 0; rt < 2; ++rt)
#pragma unroll
    for (int kd = 0; kd < 2; ++kd)
      qf[rt][kd] = *(const bf16x8*)&Qb[(size_t)(q0 + rt * 16 + j) * 64 + kd * 32 + quad * 8];

  float lrow[2] = {0.f, 0.f};
  f32x4 oacc[2][4];
  const f32x4 z4 = {0.f, 0.f, 0.f, 0.f};
#pragma unroll
  for (int rt = 0; rt < 2; ++rt)
#pragma unroll
    for (int dt = 0; dt < 4; ++dt) oacc[rt][dt] = z4;

  // stage tile 0
#pragma unroll
  for (int p = 0; p < 4; ++p) {
    int c = (p * 256 + t) * 8;
    async_ld16(Kc + c, &Ks[c]);
    async_ld16(Vc + c, &Vs[c]);
  }

  for (int it = 0; it < 8; ++it) {
    __syncthreads();  // staging drained + all waves done with previous tile

    // ---- QK^T from LDS (A = K fragment, B = Q fragment), fused exp2+pack ----
    unsigned pkd[2][8][2];  // [rt][ct][pair]: packed bf16 P, pair0=(r0,r1) pair1=(r2,r3)
#pragma unroll
    for (int ct = 0; ct < 8; ++ct) {
      bf16x8 kf0 = *(const bf16x8*)&Ks[ct * 1024 + lane * 8];
      bf16x8 kf1 = *(const bf16x8*)&Ks[ct * 1024 + 512 + lane * 8];
#pragma unroll
      for (int rt = 0; rt < 2; ++rt) {
        f32x4 sv = z4;
        sv = __builtin_amdgcn_mfma_f32_16x16x32_bf16(kf0, qf[rt][0], sv, 0, 0, 0);
        sv = __builtin_amdgcn_mfma_f32_16x16x32_bf16(kf1, qf[rt][1], sv, 0, 0, 0);
        float p0 = EXP2F(sv[0]), p1 = EXP2F(sv[1]);
        float p2 = EXP2F(sv[2]), p3 = EXP2F(sv[3]);
        lrow[rt] += (p0 + p1) + (p2 + p3);  // fp32, unquantized (accuracy-critical)
        pkd[rt][ct][0] = pack2(p0, p1);     // explicit RNE, see bf16rne
        pkd[rt][ct][1] = pack2(p2, p3);
      }
    }

    // ---- PV: A-fragments are lane-local concatenations of pkd dwords ----
#pragma unroll
    for (int kk = 0; kk < 4; ++kk) {
      union { uint4x u; bf16x8 h; } pa[2];
#pragma unroll
      for (int rt = 0; rt < 2; ++rt)
        pa[rt].u = (uint4x){pkd[rt][2 * kk][0], pkd[rt][2 * kk][1],
                            pkd[rt][2 * kk + 1][0], pkd[rt][2 * kk + 1][1]};
#pragma unroll
      for (int dt = 0; dt < 4; ++dt) {
        bf16x8 vf = *(const bf16x8*)&Vs[(kk * 4 + dt) * 512 + lane * 8];
        oacc[0][dt] = __builtin_amdgcn_mfma_f32_16x16x32_bf16(pa[0].h, vf, oacc[0][dt], 0, 0, 0);
        oacc[1][dt] = __builtin_amdgcn_mfma_f32_16x16x32_bf16(pa[1].h, vf, oacc[1][dt], 0, 0, 0);
      }
    }

    __syncthreads();  // all waves done with Ks/Vs
    if (it < 7) {
      const bf16* kn = Kc + (it + 1) * 8192;
      const bf16* vn = Vc + (it + 1) * 8192;
#pragma unroll
      for (int p = 0; p < 4; ++p) {
        int c = (p * 256 + t) * 8;
        async_ld16(kn + c, &Ks[c]);
        async_ld16(vn + c, &Vs[c]);
      }
    }
  }

  // epilogue: unnormalized partial O (fp32) + per-row l
  float* Od = ck ? O1 : O0;
#pragma unroll
  for (int rt = 0; rt < 2; ++rt) {
    // l for q = q0 + rt*16 + j lives split across the 4 quads: fold them
    float l = lrow[rt];
    l += __shfl_xor(l, 16);
    l += __shfl_xor(l, 32);
    if (quad == 0) Lp[ck * 65536 + (size_t)nh * 2048 + q0 + rt * 16 + j] = l;
#pragma unroll
    for (int r = 0; r < 4; ++r) {
      int srow = q0 + rt * 16 + quad * 4 + r;
      size_t row = (size_t)nh * 2048 + srow;
#pragma unroll
      for (int dt = 0; dt < 4; ++dt)
        Od[row * 64 + dt * 16 + j] = oacc[rt][dt][r];
    }
  }
}

// ---------------- merge two KV-chunk partials -> bf16 attn [n][s][h*64+d] ----
// Fixed-max partials: O = (O0 + O1) / (l0 + l1).
__global__ __launch_bounds__(256) void merge_kernel(const float* __restrict__ O0,
                                                    const float* __restrict__ O1,
                                                    const float* __restrict__ Lp,
                                                    bf16* __restrict__ attn) {
  int g = blockIdx.x * 256 + threadIdx.x;  // 65536 rows x 16 groups of 4 dims
  int row = g >> 4;
  int dg = (g & 15) * 4;
  float inv = 1.0f / (Lp[row] + Lp[65536 + row]);
  f32x4 a = *(const f32x4*)(O0 + (size_t)row * 64 + dg);
  f32x4 b = *(const f32x4*)(O1 + (size_t)row * 64 + dg);
  int nh = row >> 11, s = row & 2047;
  int n = nh >> 4, h = nh & 15;
  bf16x4 o;
#pragma unroll
  for (int i = 0; i < 4; ++i) o[i] = (bf16)((a[i] + b[i]) * inv);
  *(bf16x4*)(attn + ((size_t)(n * 2048 + s)) * 1024 + h * 64 + dg) = o;
}

extern "C" void kernel_launch(void* const* d_in, const int* in_sizes, int n_in,
                              void* d_out, int out_size, void* d_ws, size_t ws_size,
                              hipStream_t stream) {
  const float* x = (const float*)d_in[0];
  const float* head_mask = (const float*)d_in[1];
  const float* qkv_w = (const float*)d_in[2];
  const float* qkv_b = (const float*)d_in[3];
  const float* fc_w = (const float*)d_in[4];
  const float* fc_b = (const float*)d_in[5];
  float* out = (float*)d_out;

  char* ws = (char*)d_ws;
  bf16* x_bf    = (bf16*)(ws + 0);                    // 8 MB (later reused as attn)
  bf16* qkvw_bf = (bf16*)(ws + ((size_t)8 << 20));    // 6 MB
  bf16* fcw_bf  = (bf16*)(ws + ((size_t)14 << 20));   // 2 MB
  bf16* Qp      = (bf16*)(ws + ((size_t)16 << 20));   // 8 MB
  bf16* Kf      = (bf16*)(ws + ((size_t)24 << 20));   // 8 MB (fragment-major K, lane-local-P perm)
  bf16* Vf      = (bf16*)(ws + ((size_t)32 << 20));   // 8 MB (fragment-major V, natural order)
  float* O1     = (float*)(ws + ((size_t)40 << 20));  // 16 MB
  float* Lp     = (float*)(ws + ((size_t)56 << 20));  // 512 KB (2 chunks x 65536)
  float* O0     = (float*)d_out;  // 16 MB scratch; overwritten by gemm2 at the end
  bf16* attn = x_bf;              // x_bf dead after gemm1

  cvt3_kernel<<<8192, 256, 0, stream>>>(x, qkv_w, fc_w, x_bf, qkvw_bf, fcw_bf);
  gemm_bt_kernel<0><<<32 * 24, 256, 0, stream>>>(x_bf, qkvw_bf, qkv_b, head_mask,
                                                 Qp, Kf, Vf, nullptr, 3072, 1024, 32);
  flash_kernel<<<1024, 256, 0, stream>>>(Qp, Kf, Vf, O0, O1, Lp);
  merge_kernel<<<4096, 256, 0, stream>>>(O0, O1, Lp, attn);
  gemm_bt_kernel<1><<<32 * 8, 256, 0, stream>>>(attn, fcw_bf, fc_b, nullptr,
                                                nullptr, nullptr, nullptr, out, 1024, 1024, 32);
}

// Round 5
// 205.861 us; speedup vs baseline: 1.0641x; 1.0641x over previous
//
#include <hip/hip_runtime.h>
#include <hip/hip_bf16.h>

typedef __bf16 bf16;
typedef __attribute__((ext_vector_type(8))) __bf16 bf16x8;
typedef __attribute__((ext_vector_type(4))) __bf16 bf16x4;
typedef __attribute__((ext_vector_type(4))) float f32x4;
typedef __attribute__((ext_vector_type(4))) unsigned int uint4x;

#if __has_builtin(__builtin_amdgcn_exp2f)
#define EXP2F(x) __builtin_amdgcn_exp2f(x)
#else
#define EXP2F(x) exp2f(x)
#endif

#define AS1 __attribute__((address_space(1)))
#define AS3 __attribute__((address_space(3)))

static __device__ __forceinline__ void async_ld16(const bf16* g, bf16* l) {
  __builtin_amdgcn_global_load_lds((const AS1 void*)g, (AS3 void*)l, 16, 0, 0);
}

// f32 -> bf16 with EXPLICIT round-to-nearest-even bit arithmetic (proven in
// round 4: cvt_pk-based paths failed at ~9e-3; this passes at 2.4e-3).
// Valid for positive finite inputs (exp2 output); no NaN handling needed.
static __device__ __forceinline__ unsigned bf16rne(float x) {
  unsigned u = __float_as_uint(x);
  return (u + 0x7fffu + ((u >> 16) & 1u)) >> 16;
}
static __device__ __forceinline__ unsigned pack2(float a, float b) {
  return bf16rne(a) | (bf16rne(b) << 16);
}

// ---------------- fused fp32 -> bf16 conversion (x, qkv_w, fc_w) ----------
__global__ void cvt3_kernel(const float* __restrict__ x, const float* __restrict__ qw,
                            const float* __restrict__ fw, bf16* __restrict__ xb,
                            bf16* __restrict__ qwb, bf16* __restrict__ fwb) {
  int b = blockIdx.x;
  const float* src;
  bf16* dst;
  int i;
  if (b < 4096) { src = x; dst = xb; i = b * 256 + threadIdx.x; }
  else if (b < 7168) { src = qw; dst = qwb; i = (b - 4096) * 256 + threadIdx.x; }
  else { src = fw; dst = fwb; i = (b - 7168) * 256 + threadIdx.x; }
  f32x4 v = *(const f32x4*)(src + (size_t)i * 4);
  bf16x4 o;
  o[0] = (bf16)v[0]; o[1] = (bf16)v[1]; o[2] = (bf16)v[2]; o[3] = (bf16)v[3];
  *(bf16x4*)(dst + (size_t)i * 4) = o;
}

// ---------------- BT-GEMM: C[M,N] = A[M,K] @ B[N,K]^T ----------------
// MODE 0 epilogue: bias + head_mask; Q -> [nh][s][d] (x log2(e)/8);
//   K -> fragment-major Kf with the LANE-LOCAL-P permutation baked in:
//     key slot g (within 128-key tile) sits at QK^T C-tile ct = 2*(g>>5)+((g>>2)&1),
//     tile row i = ((g>>3)&3)*4 + (g&3). Then score for key g lands at
//     lane-quad (g>>3)&3, reg g&3 -> the PV A-fragment needs NO cross-lane
//     exchange at all (see flash_kernel).
//   V -> natural fragment-major Vf (B k-slot (quad,e) <-> key kk*32+quad*8+e).
// Both layouts are key-linear at 4096-element (64-key) granularity, so the
// flash kernel can stage half-tiles contiguously.
// MODE 1: fp32 out = acc + bias.
template <int MODE>
__global__ __launch_bounds__(256, 2) void gemm_bt_kernel(
    const bf16* __restrict__ A, const bf16* __restrict__ Bw,
    const float* __restrict__ bias, const float* __restrict__ hm,
    bf16* __restrict__ Qp, bf16* __restrict__ Kp, bf16* __restrict__ Vp,
    float* __restrict__ outF, int Ncols, int Kdim, int rowBlkCount) {
  __shared__ bf16 As[128 * 32];
  __shared__ bf16 Bs[128 * 32];
  const int t = threadIdx.x, lane = t & 63, w = t >> 6;
  const int wr = w >> 1, wc = w & 1;
  const int j = lane & 15, quad = lane >> 4;
  const int rowBlk = blockIdx.x % rowBlkCount;
  const int colBlk = blockIdx.x / rowBlkCount;
  const int rowBase = rowBlk * 128, colBase = colBlk * 128;

  f32x4 acc[4][4];
  const f32x4 z4 = {0.f, 0.f, 0.f, 0.f};
#pragma unroll
  for (int i = 0; i < 4; ++i)
#pragma unroll
    for (int jj = 0; jj < 4; ++jj) acc[i][jj] = z4;

  const int f0 = t * 8;
  const int f1 = f0 + 2048;
  const int r0 = f0 >> 5, c0 = f0 & 31;
  const int r1 = f1 >> 5, c1 = f1 & 31;

  for (int k0 = 0; k0 < Kdim; k0 += 32) {
    async_ld16(A + (size_t)(rowBase + r0) * Kdim + k0 + c0, &As[f0]);
    async_ld16(A + (size_t)(rowBase + r1) * Kdim + k0 + c1, &As[f1]);
    async_ld16(Bw + (size_t)(colBase + r0) * Kdim + k0 + c0, &Bs[f0]);
    async_ld16(Bw + (size_t)(colBase + r1) * Kdim + k0 + c1, &Bs[f1]);
    __syncthreads();
    bf16x8 af[4], bfr[4];
#pragma unroll
    for (int i = 0; i < 4; ++i)
      af[i] = *(const bf16x8*)&As[(wr * 64 + i * 16 + j) * 32 + quad * 8];
#pragma unroll
    for (int jj = 0; jj < 4; ++jj)
      bfr[jj] = *(const bf16x8*)&Bs[(wc * 64 + jj * 16 + j) * 32 + quad * 8];
#pragma unroll
    for (int i = 0; i < 4; ++i)
#pragma unroll
      for (int jj = 0; jj < 4; ++jj)
        acc[i][jj] = __builtin_amdgcn_mfma_f32_16x16x32_bf16(af[i], bfr[jj], acc[i][jj], 0, 0, 0);
    __syncthreads();
  }

  if (MODE == 0) {
#pragma unroll
    for (int jj = 0; jj < 4; ++jj) {
      int col = colBase + wc * 64 + jj * 16 + j;
      int hh = col / 192;
      int rem = col - hh * 192;
      int mm = rem >> 6;   // wave-uniform (16-col runs never cross a 64 boundary)
      int dd = rem & 63;
      float hmv = hm[hh];
      float bv = bias[col];
      float sc = (mm == 0) ? hmv * 0.18033688011112042f : hmv;  // log2(e)/8 folded into Q
#pragma unroll
      for (int i = 0; i < 4; ++i) {
#pragma unroll
        for (int r = 0; r < 4; ++r) {
          int row = rowBase + wr * 64 + i * 16 + quad * 4 + r;
          int n = row >> 11, ss = row & 2047;
          size_t nh = (size_t)(n * 16 + hh);
          float val = (acc[i][jj][r] + bv) * sc;
          if (mm == 0) {
            Qp[nh * 131072 + ss * 64 + dd] = (bf16)val;
          } else if (mm == 1) {
            // lane-local-P Kf: g = ss&127, T = ss>>7,
            // ct = 2*((g>>5)&3) + ((g>>2)&1), i = ((g>>3)&3)*4 + (g&3)
            size_t idx = nh * 131072 + (size_t)(ss >> 7) * 8192 +
                         (size_t)(2 * ((ss >> 5) & 3) + ((ss >> 2) & 1)) * 1024 +
                         (dd >> 5) * 512 + ((dd >> 3) & 3) * 128 +
                         (((ss >> 3) & 3) * 4 + (ss & 3)) * 8 + (dd & 7);
            Kp[idx] = (bf16)val;
          } else {
            // natural fragment-major V: tile (ss>>7), block (kk=(ss>>5)&3, dt=dd>>4),
            // within block quad=(ss>>3)&3, j=dd&15, elem=ss&7
            size_t idx = nh * 131072 + (size_t)(ss >> 7) * 8192 +
                         (((ss >> 5) & 3) * 4 + (dd >> 4)) * 512 +
                         ((ss >> 3) & 3) * 128 + (dd & 15) * 8 + (ss & 7);
            Vp[idx] = (bf16)val;
          }
        }
      }
    }
  } else {
#pragma unroll
    for (int jj = 0; jj < 4; ++jj) {
      int col = colBase + wc * 64 + jj * 16 + j;
      float bv = bias[col];
#pragma unroll
      for (int i = 0; i < 4; ++i)
#pragma unroll
        for (int r = 0; r < 4; ++r) {
          int row = rowBase + wr * 64 + i * 16 + quad * 4 + r;
          outF[(size_t)row * Ncols + col] = acc[i][jj][r] + bv;
        }
    }
  }
}

// ---------------- Flash attention: swapped QK^T, lane-local P, PIPELINED ----
// grid = 1024: b = qt*64 + nh*2 + ck. Block = 128 q-rows (4 waves x 32).
// ROUND-5 CHANGE (one variable): 2-phase double-buffered staging.
// Round-4 counters showed ~45% idle per iteration-slot (MfmaUtil 18.5 +
// VALUBusy 34, occupancy 33, HBM 31 -- nothing saturated): the prefetch was
// issued at the END of the iteration and the loop-top __syncthreads drains
// vmcnt(0) immediately -> zero overlap, full global->LDS latency exposed
// every iteration for every wave. New structure per 64-key sub-tile:
//   barrier -> issue stage(buf^1, t+1) -> compute(buf) -> (next barrier)
// so the vmcnt(0) drain at each barrier waits on loads issued one full
// compute phase (~2K cy) earlier => steady-state exposed latency ~0.
// Sub-tiles are contiguous 4096-elem halves of the 8192-elem fragment tiles
// (ct 0-3 = keys 0-63, kk 0-1 = keys 0-63), so staging stays 16B-linear.
// LDS: 2 bufs x (8KB K + 8KB V) = 32KB => 4 blocks/CU, grid fully resident.
// All P math / layouts / epilogue byte-identical to the passing round 4.
#define FLASH_STAGE(tileIdx, KsBuf, VsBuf)                                  \
  {                                                                         \
    const bf16* kn_ = Kc + (tileIdx) * 4096;                                \
    const bf16* vn_ = Vc + (tileIdx) * 4096;                                \
    _Pragma("unroll")                                                       \
    for (int p = 0; p < 2; ++p) {                                           \
      int c = (p * 256 + t) * 8;                                            \
      async_ld16(kn_ + c, &KsBuf[c]);                                       \
      async_ld16(vn_ + c, &VsBuf[c]);                                       \
    }                                                                       \
  }

#define FLASH_TILE(KsBuf, VsBuf)                                            \
  {                                                                         \
    unsigned pkd[2][4][2];                                                  \
    _Pragma("unroll")                                                       \
    for (int ct = 0; ct < 4; ++ct) {                                        \
      bf16x8 kf0 = *(const bf16x8*)&KsBuf[ct * 1024 + lane * 8];            \
      bf16x8 kf1 = *(const bf16x8*)&KsBuf[ct * 1024 + 512 + lane * 8];      \
      _Pragma("unroll")                                                     \
      for (int rt = 0; rt < 2; ++rt) {                                      \
        f32x4 sv = z4;                                                      \
        sv = __builtin_amdgcn_mfma_f32_16x16x32_bf16(kf0, qf[rt][0], sv, 0, 0, 0); \
        sv = __builtin_amdgcn_mfma_f32_16x16x32_bf16(kf1, qf[rt][1], sv, 0, 0, 0); \
        float p0 = EXP2F(sv[0]), p1 = EXP2F(sv[1]);                         \
        float p2 = EXP2F(sv[2]), p3 = EXP2F(sv[3]);                         \
        lrow[rt] += (p0 + p1) + (p2 + p3);                                  \
        pkd[rt][ct][0] = pack2(p0, p1);                                     \
        pkd[rt][ct][1] = pack2(p2, p3);                                     \
      }                                                                     \
    }                                                                       \
    _Pragma("unroll")                                                       \
    for (int kk = 0; kk < 2; ++kk) {                                        \
      union { uint4x u; bf16x8 h; } pa[2];                                  \
      _Pragma("unroll")                                                     \
      for (int rt = 0; rt < 2; ++rt)                                        \
        pa[rt].u = (uint4x){pkd[rt][2 * kk][0], pkd[rt][2 * kk][1],         \
                            pkd[rt][2 * kk + 1][0], pkd[rt][2 * kk + 1][1]};\
      _Pragma("unroll")                                                     \
      for (int dt = 0; dt < 4; ++dt) {                                      \
        bf16x8 vf = *(const bf16x8*)&VsBuf[(kk * 4 + dt) * 512 + lane * 8]; \
        oacc[0][dt] = __builtin_amdgcn_mfma_f32_16x16x32_bf16(pa[0].h, vf, oacc[0][dt], 0, 0, 0); \
        oacc[1][dt] = __builtin_amdgcn_mfma_f32_16x16x32_bf16(pa[1].h, vf, oacc[1][dt], 0, 0, 0); \
      }                                                                     \
    }                                                                       \
  }

__global__ __launch_bounds__(256, 4) void flash_kernel(const bf16* __restrict__ Qp,
                                                       const bf16* __restrict__ Kf,
                                                       const bf16* __restrict__ Vf,
                                                       float* __restrict__ O0,
                                                       float* __restrict__ O1,
                                                       float* __restrict__ Lp) {
  __shared__ bf16 Ks0[4096];
  __shared__ bf16 Vs0[4096];
  __shared__ bf16 Ks1[4096];
  __shared__ bf16 Vs1[4096];
  const int t = threadIdx.x, lane = t & 63, w = t >> 6;
  const int j = lane & 15, quad = lane >> 4;
  const int g = blockIdx.x & 63;
  const int qt = blockIdx.x >> 6;   // [0,16)
  const int nh = g >> 1, ck = g & 1;
  const int q0 = qt * 128 + w * 32;
  const bf16* Qb = Qp + (size_t)nh * 131072;
  const bf16* Kc = Kf + (size_t)nh * 131072 + ck * 65536;
  const bf16* Vc = Vf + (size_t)nh * 131072 + ck * 65536;

  bf16x8 qf[2][2];
#pragma unroll
  for (int rt = 0; rt < 2; ++rt)
#pragma unroll
    for (int kd = 0; kd < 2; ++kd)
      qf[rt][kd] = *(const bf16x8*)&Qb[(size_t)(q0 + rt * 16 + j) * 64 + kd * 32 + quad * 8];

  float lrow[2] = {0.f, 0.f};
  f32x4 oacc[2][4];
  const f32x4 z4 = {0.f, 0.f, 0.f, 0.f};
#pragma unroll
  for (int rt = 0; rt < 2; ++rt)
#pragma unroll
    for (int dt = 0; dt < 4; ++dt) oacc[rt][dt] = z4;

  // prologue: stage sub-tile 0 into buffer 0 (only this one is unoverlapped)
  FLASH_STAGE(0, Ks0, Vs0);

  for (int it2 = 0; it2 < 8; ++it2) {
    __syncthreads();  // drains buf0 staging; all waves done reading buf1
    FLASH_STAGE(it2 * 2 + 1, Ks1, Vs1);   // overlaps with compute below
    FLASH_TILE(Ks0, Vs0);
    __syncthreads();  // drains buf1 staging; all waves done reading buf0
    if (it2 < 7) FLASH_STAGE(it2 * 2 + 2, Ks0, Vs0);
    FLASH_TILE(Ks1, Vs1);
  }

  // epilogue: unnormalized partial O (fp32) + per-row l
  float* Od = ck ? O1 : O0;
#pragma unroll
  for (int rt = 0; rt < 2; ++rt) {
    // l for q = q0 + rt*16 + j lives split across the 4 quads: fold them
    float l = lrow[rt];
    l += __shfl_xor(l, 16);
    l += __shfl_xor(l, 32);
    if (quad == 0) Lp[ck * 65536 + (size_t)nh * 2048 + q0 + rt * 16 + j] = l;
#pragma unroll
    for (int r = 0; r < 4; ++r) {
      int srow = q0 + rt * 16 + quad * 4 + r;
      size_t row = (size_t)nh * 2048 + srow;
#pragma unroll
      for (int dt = 0; dt < 4; ++dt)
        Od[row * 64 + dt * 16 + j] = oacc[rt][dt][r];
    }
  }
}

// ---------------- merge two KV-chunk partials -> bf16 attn [n][s][h*64+d] ----
// Fixed-max partials: O = (O0 + O1) / (l0 + l1).
__global__ __launch_bounds__(256) void merge_kernel(const float* __restrict__ O0,
                                                    const float* __restrict__ O1,
                                                    const float* __restrict__ Lp,
                                                    bf16* __restrict__ attn) {
  int g = blockIdx.x * 256 + threadIdx.x;  // 65536 rows x 16 groups of 4 dims
  int row = g >> 4;
  int dg = (g & 15) * 4;
  float inv = 1.0f / (Lp[row] + Lp[65536 + row]);
  f32x4 a = *(const f32x4*)(O0 + (size_t)row * 64 + dg);
  f32x4 b = *(const f32x4*)(O1 + (size_t)row * 64 + dg);
  int nh = row >> 11, s = row & 2047;
  int n = nh >> 4, h = nh & 15;
  bf16x4 o;
#pragma unroll
  for (int i = 0; i < 4; ++i) o[i] = (bf16)((a[i] + b[i]) * inv);
  *(bf16x4*)(attn + ((size_t)(n * 2048 + s)) * 1024 + h * 64 + dg) = o;
}

extern "C" void kernel_launch(void* const* d_in, const int* in_sizes, int n_in,
                              void* d_out, int out_size, void* d_ws, size_t ws_size,
                              hipStream_t stream) {
  const float* x = (const float*)d_in[0];
  const float* head_mask = (const float*)d_in[1];
  const float* qkv_w = (const float*)d_in[2];
  const float* qkv_b = (const float*)d_in[3];
  const float* fc_w = (const float*)d_in[4];
  const float* fc_b = (const float*)d_in[5];
  float* out = (float*)d_out;

  char* ws = (char*)d_ws;
  bf16* x_bf    = (bf16*)(ws + 0);                    // 8 MB (later reused as attn)
  bf16* qkvw_bf = (bf16*)(ws + ((size_t)8 << 20));    // 6 MB
  bf16* fcw_bf  = (bf16*)(ws + ((size_t)14 << 20));   // 2 MB
  bf16* Qp      = (bf16*)(ws + ((size_t)16 << 20));   // 8 MB
  bf16* Kf      = (bf16*)(ws + ((size_t)24 << 20));   // 8 MB (fragment-major K, lane-local-P perm)
  bf16* Vf      = (bf16*)(ws + ((size_t)32 << 20));   // 8 MB (fragment-major V, natural order)
  float* O1     = (float*)(ws + ((size_t)40 << 20));  // 16 MB
  float* Lp     = (float*)(ws + ((size_t)56 << 20));  // 512 KB (2 chunks x 65536)
  float* O0     = (float*)d_out;  // 16 MB scratch; overwritten by gemm2 at the end
  bf16* attn = x_bf;              // x_bf dead after gemm1

  cvt3_kernel<<<8192, 256, 0, stream>>>(x, qkv_w, fc_w, x_bf, qkvw_bf, fcw_bf);
  gemm_bt_kernel<0><<<32 * 24, 256, 0, stream>>>(x_bf, qkvw_bf, qkv_b, head_mask,
                                                 Qp, Kf, Vf, nullptr, 3072, 1024, 32);
  flash_kernel<<<1024, 256, 0, stream>>>(Qp, Kf, Vf, O0, O1, Lp);
  merge_kernel<<<4096, 256, 0, stream>>>(O0, O1, Lp, attn);
  gemm_bt_kernel<1><<<32 * 8, 256, 0, stream>>>(attn, fcw_bf, fc_b, nullptr,
                                                nullptr, nullptr, nullptr, out, 1024, 1024, 32);
}

// Round 6
// 204.062 us; speedup vs baseline: 1.0735x; 1.0088x over previous
//
#include <hip/hip_runtime.h>
#include <hip/hip_bf16.h>

typedef __bf16 bf16;
typedef __attribute__((ext_vector_type(8))) __bf16 bf16x8;
typedef __attribute__((ext_vector_type(4))) __bf16 bf16x4;
typedef __attribute__((ext_vector_type(4))) float f32x4;
typedef __attribute__((ext_vector_type(4))) unsigned int uint4x;

#if __has_builtin(__builtin_amdgcn_exp2f)
#define EXP2F(x) __builtin_amdgcn_exp2f(x)
#else
#define EXP2F(x) exp2f(x)
#endif

#define AS1 __attribute__((address_space(1)))
#define AS3 __attribute__((address_space(3)))

static __device__ __forceinline__ void async_ld16(const bf16* g, bf16* l) {
  __builtin_amdgcn_global_load_lds((const AS1 void*)g, (AS3 void*)l, 16, 0, 0);
}

// f32 -> bf16 with EXPLICIT round-to-nearest-even bit arithmetic (proven in
// round 4: cvt_pk-based paths failed at ~9e-3; this passes at 2.4e-3).
// Valid for positive finite inputs (exp2 output); no NaN handling needed.
static __device__ __forceinline__ unsigned bf16rne(float x) {
  unsigned u = __float_as_uint(x);
  return (u + 0x7fffu + ((u >> 16) & 1u)) >> 16;
}
static __device__ __forceinline__ unsigned pack2(float a, float b) {
  return bf16rne(a) | (bf16rne(b) << 16);
}

// ---------------- fused fp32 -> bf16 conversion (x, qkv_w, fc_w) ----------
__global__ void cvt3_kernel(const float* __restrict__ x, const float* __restrict__ qw,
                            const float* __restrict__ fw, bf16* __restrict__ xb,
                            bf16* __restrict__ qwb, bf16* __restrict__ fwb) {
  int b = blockIdx.x;
  const float* src;
  bf16* dst;
  int i;
  if (b < 4096) { src = x; dst = xb; i = b * 256 + threadIdx.x; }
  else if (b < 7168) { src = qw; dst = qwb; i = (b - 4096) * 256 + threadIdx.x; }
  else { src = fw; dst = fwb; i = (b - 7168) * 256 + threadIdx.x; }
  f32x4 v = *(const f32x4*)(src + (size_t)i * 4);
  bf16x4 o;
  o[0] = (bf16)v[0]; o[1] = (bf16)v[1]; o[2] = (bf16)v[2]; o[3] = (bf16)v[3];
  *(bf16x4*)(dst + (size_t)i * 4) = o;
}

// ---------------- BT-GEMM: C[M,N] = A[M,K] @ B[N,K]^T ----------------
// ROUND-6 CHANGE (one variable): 2-phase double-buffered K-loop, same
// hazard-checked pattern that took flash 72.8->57.6 us in round 5. Old loop
// paid TWO barriers per 32-wide K-step and drained vmcnt(0) immediately
// after issuing the staging (zero overlap). New loop: prologue-stage buf0;
// per K-step {sync -> stage(buf^1, k0+32) -> compute(buf)} -- ONE barrier
// per K-step, and the drain at each barrier waits on loads issued one full
// MFMA phase earlier. Hazard check: iter i's sync guarantees (a) staging of
// buf (issued iter i-1) complete [syncthreads drains vmcnt], (b) all waves
// finished iter i-1's reads of buf^1 [syncthreads drains lgkm + barrier],
// so overwriting buf^1 is safe. LDS 16->32 KB.
// MODE 0 epilogue: bias + head_mask; Q -> [nh][s][d] (x log2(e)/8);
//   K -> fragment-major Kf with the LANE-LOCAL-P permutation baked in
//     (key g at C-tile ct = 2*(g>>5)+((g>>2)&1), row i = ((g>>3)&3)*4+(g&3));
//   V -> natural fragment-major Vf. Both key-linear at 64-key granularity.
// MODE 1: fp32 out = acc + bias.
#define GEMM_STAGE(k0_, buf_)                                                   \
  {                                                                             \
    async_ld16(A + (size_t)(rowBase + r0) * Kdim + (k0_) + c0, &As[buf_][f0]);  \
    async_ld16(A + (size_t)(rowBase + r1) * Kdim + (k0_) + c1, &As[buf_][f1]);  \
    async_ld16(Bw + (size_t)(colBase + r0) * Kdim + (k0_) + c0, &Bs[buf_][f0]); \
    async_ld16(Bw + (size_t)(colBase + r1) * Kdim + (k0_) + c1, &Bs[buf_][f1]); \
  }

template <int MODE>
__global__ __launch_bounds__(256, 2) void gemm_bt_kernel(
    const bf16* __restrict__ A, const bf16* __restrict__ Bw,
    const float* __restrict__ bias, const float* __restrict__ hm,
    bf16* __restrict__ Qp, bf16* __restrict__ Kp, bf16* __restrict__ Vp,
    float* __restrict__ outF, int Ncols, int Kdim, int rowBlkCount) {
  __shared__ bf16 As[2][128 * 32];
  __shared__ bf16 Bs[2][128 * 32];
  const int t = threadIdx.x, lane = t & 63, w = t >> 6;
  const int wr = w >> 1, wc = w & 1;
  const int j = lane & 15, quad = lane >> 4;
  const int rowBlk = blockIdx.x % rowBlkCount;
  const int colBlk = blockIdx.x / rowBlkCount;
  const int rowBase = rowBlk * 128, colBase = colBlk * 128;

  f32x4 acc[4][4];
  const f32x4 z4 = {0.f, 0.f, 0.f, 0.f};
#pragma unroll
  for (int i = 0; i < 4; ++i)
#pragma unroll
    for (int jj = 0; jj < 4; ++jj) acc[i][jj] = z4;

  const int f0 = t * 8;
  const int f1 = f0 + 2048;
  const int r0 = f0 >> 5, c0 = f0 & 31;
  const int r1 = f1 >> 5, c1 = f1 & 31;

  GEMM_STAGE(0, 0);
  int buf = 0;
  for (int k0 = 0; k0 < Kdim; k0 += 32) {
    __syncthreads();  // buf staged; all waves done reading buf^1
    if (k0 + 32 < Kdim) GEMM_STAGE(k0 + 32, buf ^ 1);  // overlaps compute below
    bf16x8 af[4], bfr[4];
#pragma unroll
    for (int i = 0; i < 4; ++i)
      af[i] = *(const bf16x8*)&As[buf][(wr * 64 + i * 16 + j) * 32 + quad * 8];
#pragma unroll
    for (int jj = 0; jj < 4; ++jj)
      bfr[jj] = *(const bf16x8*)&Bs[buf][(wc * 64 + jj * 16 + j) * 32 + quad * 8];
#pragma unroll
    for (int i = 0; i < 4; ++i)
#pragma unroll
      for (int jj = 0; jj < 4; ++jj)
        acc[i][jj] = __builtin_amdgcn_mfma_f32_16x16x32_bf16(af[i], bfr[jj], acc[i][jj], 0, 0, 0);
    buf ^= 1;
  }

  if (MODE == 0) {
#pragma unroll
    for (int jj = 0; jj < 4; ++jj) {
      int col = colBase + wc * 64 + jj * 16 + j;
      int hh = col / 192;
      int rem = col - hh * 192;
      int mm = rem >> 6;   // wave-uniform (16-col runs never cross a 64 boundary)
      int dd = rem & 63;
      float hmv = hm[hh];
      float bv = bias[col];
      float sc = (mm == 0) ? hmv * 0.18033688011112042f : hmv;  // log2(e)/8 folded into Q
#pragma unroll
      for (int i = 0; i < 4; ++i) {
#pragma unroll
        for (int r = 0; r < 4; ++r) {
          int row = rowBase + wr * 64 + i * 16 + quad * 4 + r;
          int n = row >> 11, ss = row & 2047;
          size_t nh = (size_t)(n * 16 + hh);
          float val = (acc[i][jj][r] + bv) * sc;
          if (mm == 0) {
            Qp[nh * 131072 + ss * 64 + dd] = (bf16)val;
          } else if (mm == 1) {
            // lane-local-P Kf: g = ss&127, T = ss>>7,
            // ct = 2*((g>>5)&3) + ((g>>2)&1), i = ((g>>3)&3)*4 + (g&3)
            size_t idx = nh * 131072 + (size_t)(ss >> 7) * 8192 +
                         (size_t)(2 * ((ss >> 5) & 3) + ((ss >> 2) & 1)) * 1024 +
                         (dd >> 5) * 512 + ((dd >> 3) & 3) * 128 +
                         (((ss >> 3) & 3) * 4 + (ss & 3)) * 8 + (dd & 7);
            Kp[idx] = (bf16)val;
          } else {
            // natural fragment-major V: tile (ss>>7), block (kk=(ss>>5)&3, dt=dd>>4),
            // within block quad=(ss>>3)&3, j=dd&15, elem=ss&7
            size_t idx = nh * 131072 + (size_t)(ss >> 7) * 8192 +
                         (((ss >> 5) & 3) * 4 + (dd >> 4)) * 512 +
                         ((ss >> 3) & 3) * 128 + (dd & 15) * 8 + (ss & 7);
            Vp[idx] = (bf16)val;
          }
        }
      }
    }
  } else {
#pragma unroll
    for (int jj = 0; jj < 4; ++jj) {
      int col = colBase + wc * 64 + jj * 16 + j;
      float bv = bias[col];
#pragma unroll
      for (int i = 0; i < 4; ++i)
#pragma unroll
        for (int r = 0; r < 4; ++r) {
          int row = rowBase + wr * 64 + i * 16 + quad * 4 + r;
          outF[(size_t)row * Ncols + col] = acc[i][jj][r] + bv;
        }
    }
  }
}

// ---------------- Flash attention: swapped QK^T, lane-local P, PIPELINED ----
// (unchanged from the passing round 5: 2-phase double-buffered staging,
// lane-local in-register P via Kf permutation, explicit-RNE pack, fixed-max
// softmax, fp32 l. LDS 32KB => 4 blocks/CU, grid 1024 fully resident.)
#define FLASH_STAGE(tileIdx, KsBuf, VsBuf)                                  \
  {                                                                         \
    const bf16* kn_ = Kc + (tileIdx) * 4096;                                \
    const bf16* vn_ = Vc + (tileIdx) * 4096;                                \
    _Pragma("unroll")                                                       \
    for (int p = 0; p < 2; ++p) {                                           \
      int c = (p * 256 + t) * 8;                                            \
      async_ld16(kn_ + c, &KsBuf[c]);                                       \
      async_ld16(vn_ + c, &VsBuf[c]);                                       \
    }                                                                       \
  }

#define FLASH_TILE(KsBuf, VsBuf)                                            \
  {                                                                         \
    unsigned pkd[2][4][2];                                                  \
    _Pragma("unroll")                                                       \
    for (int ct = 0; ct < 4; ++ct) {                                        \
      bf16x8 kf0 = *(const bf16x8*)&KsBuf[ct * 1024 + lane * 8];            \
      bf16x8 kf1 = *(const bf16x8*)&KsBuf[ct * 1024 + 512 + lane * 8];      \
      _Pragma("unroll")                                                     \
      for (int rt = 0; rt < 2; ++rt) {                                      \
        f32x4 sv = z4;                                                      \
        sv = __builtin_amdgcn_mfma_f32_16x16x32_bf16(kf0, qf[rt][0], sv, 0, 0, 0); \
        sv = __builtin_amdgcn_mfma_f32_16x16x32_bf16(kf1, qf[rt][1], sv, 0, 0, 0); \
        float p0 = EXP2F(sv[0]), p1 = EXP2F(sv[1]);                         \
        float p2 = EXP2F(sv[2]), p3 = EXP2F(sv[3]);                         \
        lrow[rt] += (p0 + p1) + (p2 + p3);                                  \
        pkd[rt][ct][0] = pack2(p0, p1);                                     \
        pkd[rt][ct][1] = pack2(p2, p3);                                     \
      }                                                                     \
    }                                                                       \
    _Pragma("unroll")                                                       \
    for (int kk = 0; kk < 2; ++kk) {                                        \
      union { uint4x u; bf16x8 h; } pa[2];                                  \
      _Pragma("unroll")                                                     \
      for (int rt = 0; rt < 2; ++rt)                                        \
        pa[rt].u = (uint4x){pkd[rt][2 * kk][0], pkd[rt][2 * kk][1],         \
                            pkd[rt][2 * kk + 1][0], pkd[rt][2 * kk + 1][1]};\
      _Pragma("unroll")                                                     \
      for (int dt = 0; dt < 4; ++dt) {                                      \
        bf16x8 vf = *(const bf16x8*)&VsBuf[(kk * 4 + dt) * 512 + lane * 8]; \
        oacc[0][dt] = __builtin_amdgcn_mfma_f32_16x16x32_bf16(pa[0].h, vf, oacc[0][dt], 0, 0, 0); \
        oacc[1][dt] = __builtin_amdgcn_mfma_f32_16x16x32_bf16(pa[1].h, vf, oacc[1][dt], 0, 0, 0); \
      }                                                                     \
    }                                                                       \
  }

__global__ __launch_bounds__(256, 4) void flash_kernel(const bf16* __restrict__ Qp,
                                                       const bf16* __restrict__ Kf,
                                                       const bf16* __restrict__ Vf,
                                                       float* __restrict__ O0,
                                                       float* __restrict__ O1,
                                                       float* __restrict__ Lp) {
  __shared__ bf16 Ks0[4096];
  __shared__ bf16 Vs0[4096];
  __shared__ bf16 Ks1[4096];
  __shared__ bf16 Vs1[4096];
  const int t = threadIdx.x, lane = t & 63, w = t >> 6;
  const int j = lane & 15, quad = lane >> 4;
  const int g = blockIdx.x & 63;
  const int qt = blockIdx.x >> 6;   // [0,16)
  const int nh = g >> 1, ck = g & 1;
  const int q0 = qt * 128 + w * 32;
  const bf16* Qb = Qp + (size_t)nh * 131072;
  const bf16* Kc = Kf + (size_t)nh * 131072 + ck * 65536;
  const bf16* Vc = Vf + (size_t)nh * 131072 + ck * 65536;

  bf16x8 qf[2][2];
#pragma unroll
  for (int rt = 0; rt < 2; ++rt)
#pragma unroll
    for (int kd = 0; kd < 2; ++kd)
      qf[rt][kd] = *(const bf16x8*)&Qb[(size_t)(q0 + rt * 16 + j) * 64 + kd * 32 + quad * 8];

  float lrow[2] = {0.f, 0.f};
  f32x4 oacc[2][4];
  const f32x4 z4 = {0.f, 0.f, 0.f, 0.f};
#pragma unroll
  for (int rt = 0; rt < 2; ++rt)
#pragma unroll
    for (int dt = 0; dt < 4; ++dt) oacc[rt][dt] = z4;

  // prologue: stage sub-tile 0 into buffer 0 (only this one is unoverlapped)
  FLASH_STAGE(0, Ks0, Vs0);

  for (int it2 = 0; it2 < 8; ++it2) {
    __syncthreads();  // drains buf0 staging; all waves done reading buf1
    FLASH_STAGE(it2 * 2 + 1, Ks1, Vs1);   // overlaps with compute below
    FLASH_TILE(Ks0, Vs0);
    __syncthreads();  // drains buf1 staging; all waves done reading buf0
    if (it2 < 7) FLASH_STAGE(it2 * 2 + 2, Ks0, Vs0);
    FLASH_TILE(Ks1, Vs1);
  }

  // epilogue: unnormalized partial O (fp32) + per-row l
  float* Od = ck ? O1 : O0;
#pragma unroll
  for (int rt = 0; rt < 2; ++rt) {
    // l for q = q0 + rt*16 + j lives split across the 4 quads: fold them
    float l = lrow[rt];
    l += __shfl_xor(l, 16);
    l += __shfl_xor(l, 32);
    if (quad == 0) Lp[ck * 65536 + (size_t)nh * 2048 + q0 + rt * 16 + j] = l;
#pragma unroll
    for (int r = 0; r < 4; ++r) {
      int srow = q0 + rt * 16 + quad * 4 + r;
      size_t row = (size_t)nh * 2048 + srow;
#pragma unroll
      for (int dt = 0; dt < 4; ++dt)
        Od[row * 64 + dt * 16 + j] = oacc[rt][dt][r];
    }
  }
}

// ---------------- merge two KV-chunk partials -> bf16 attn [n][s][h*64+d] ----
// Fixed-max partials: O = (O0 + O1) / (l0 + l1).
__global__ __launch_bounds__(256) void merge_kernel(const float* __restrict__ O0,
                                                    const float* __restrict__ O1,
                                                    const float* __restrict__ Lp,
                                                    bf16* __restrict__ attn) {
  int g = blockIdx.x * 256 + threadIdx.x;  // 65536 rows x 16 groups of 4 dims
  int row = g >> 4;
  int dg = (g & 15) * 4;
  float inv = 1.0f / (Lp[row] + Lp[65536 + row]);
  f32x4 a = *(const f32x4*)(O0 + (size_t)row * 64 + dg);
  f32x4 b = *(const f32x4*)(O1 + (size_t)row * 64 + dg);
  int nh = row >> 11, s = row & 2047;
  int n = nh >> 4, h = nh & 15;
  bf16x4 o;
#pragma unroll
  for (int i = 0; i < 4; ++i) o[i] = (bf16)((a[i] + b[i]) * inv);
  *(bf16x4*)(attn + ((size_t)(n * 2048 + s)) * 1024 + h * 64 + dg) = o;
}

extern "C" void kernel_launch(void* const* d_in, const int* in_sizes, int n_in,
                              void* d_out, int out_size, void* d_ws, size_t ws_size,
                              hipStream_t stream) {
  const float* x = (const float*)d_in[0];
  const float* head_mask = (const float*)d_in[1];
  const float* qkv_w = (const float*)d_in[2];
  const float* qkv_b = (const float*)d_in[3];
  const float* fc_w = (const float*)d_in[4];
  const float* fc_b = (const float*)d_in[5];
  float* out = (float*)d_out;

  char* ws = (char*)d_ws;
  bf16* x_bf    = (bf16*)(ws + 0);                    // 8 MB (later reused as attn)
  bf16* qkvw_bf = (bf16*)(ws + ((size_t)8 << 20));    // 6 MB
  bf16* fcw_bf  = (bf16*)(ws + ((size_t)14 << 20));   // 2 MB
  bf16* Qp      = (bf16*)(ws + ((size_t)16 << 20));   // 8 MB
  bf16* Kf      = (bf16*)(ws + ((size_t)24 << 20));   // 8 MB (fragment-major K, lane-local-P perm)
  bf16* Vf      = (bf16*)(ws + ((size_t)32 << 20));   // 8 MB (fragment-major V, natural order)
  float* O1     = (float*)(ws + ((size_t)40 << 20));  // 16 MB
  float* Lp     = (float*)(ws + ((size_t)56 << 20));  // 512 KB (2 chunks x 65536)
  float* O0     = (float*)d_out;  // 16 MB scratch; overwritten by gemm2 at the end
  bf16* attn = x_bf;              // x_bf dead after gemm1

  cvt3_kernel<<<8192, 256, 0, stream>>>(x, qkv_w, fc_w, x_bf, qkvw_bf, fcw_bf);
  gemm_bt_kernel<0><<<32 * 24, 256, 0, stream>>>(x_bf, qkvw_bf, qkv_b, head_mask,
                                                 Qp, Kf, Vf, nullptr, 3072, 1024, 32);
  flash_kernel<<<1024, 256, 0, stream>>>(Qp, Kf, Vf, O0, O1, Lp);
  merge_kernel<<<4096, 256, 0, stream>>>(O0, O1, Lp, attn);
  gemm_bt_kernel<1><<<32 * 8, 256, 0, stream>>>(attn, fcw_bf, fc_b, nullptr,
                                                nullptr, nullptr, nullptr, out, 1024, 1024, 32);
}

// Round 8
// 203.082 us; speedup vs baseline: 1.0787x; 1.0048x over previous
//
#include <hip/hip_runtime.h>
#include <hip/hip_bf16.h>

typedef __bf16 bf16;
typedef __attribute__((ext_vector_type(8))) __bf16 bf16x8;
typedef __attribute__((ext_vector_type(4))) __bf16 bf16x4;
typedef __attribute__((ext_vector_type(4))) float f32x4;
typedef __attribute__((ext_vector_type(4))) unsigned int uint4x;

#if __has_builtin(__builtin_amdgcn_exp2f)
#define EXP2F(x) __builtin_amdgcn_exp2f(x)
#else
#define EXP2F(x) exp2f(x)
#endif

#define AS1 __attribute__((address_space(1)))
#define AS3 __attribute__((address_space(3)))

static __device__ __forceinline__ void async_ld16(const bf16* g, bf16* l) {
  __builtin_amdgcn_global_load_lds((const AS1 void*)g, (AS3 void*)l, 16, 0, 0);
}

// f32 -> bf16 with EXPLICIT round-to-nearest-even bit arithmetic (proven in
// round 4: cvt_pk-based paths failed at ~9e-3; this passes at 2.4e-3).
// Valid for positive finite inputs (exp2 output); no NaN handling needed.
static __device__ __forceinline__ unsigned bf16rne(float x) {
  unsigned u = __float_as_uint(x);
  return (u + 0x7fffu + ((u >> 16) & 1u)) >> 16;
}
static __device__ __forceinline__ unsigned pack2(float a, float b) {
  return bf16rne(a) | (bf16rne(b) << 16);
}

// ---------------- fused fp32 -> bf16 conversion (x, qkv_w, fc_w) ----------
__global__ void cvt3_kernel(const float* __restrict__ x, const float* __restrict__ qw,
                            const float* __restrict__ fw, bf16* __restrict__ xb,
                            bf16* __restrict__ qwb, bf16* __restrict__ fwb) {
  int b = blockIdx.x;
  const float* src;
  bf16* dst;
  int i;
  if (b < 4096) { src = x; dst = xb; i = b * 256 + threadIdx.x; }
  else if (b < 7168) { src = qw; dst = qwb; i = (b - 4096) * 256 + threadIdx.x; }
  else { src = fw; dst = fwb; i = (b - 7168) * 256 + threadIdx.x; }
  f32x4 v = *(const f32x4*)(src + (size_t)i * 4);
  bf16x4 o;
  o[0] = (bf16)v[0]; o[1] = (bf16)v[1]; o[2] = (bf16)v[2]; o[3] = (bf16)v[3];
  *(bf16x4*)(dst + (size_t)i * 4) = o;
}

// ---------------- BT-GEMM: C[M,N] = A[M,K] @ B[N,K]^T ----------------
// T2 XOR-swizzle for the LDS fragment reads (round-7, resubmitted verbatim
// after infra failure). Round-6 post-mortem: the fragment read
// As[row*32 + quad*8] puts each consecutive-8-lane service phase on only 2
// bank-groups (4-way conflict, ~1.58x m136), making the K-loop LDS-bound --
// which is why round-6's staging overlap was null.
// Fix per rule #21 / m173: LDS dest stays LINEAR (global_load_lds needs it);
// the GLOBAL source column granule is pre-swizzled with ^= (row>>1)&3, and
// the fragment read applies the same XOR (involution verified). Swizzled
// read phases hit all 8 bank-groups -> conflict-free (same pattern class as
// flash's lane*8 reads, which measure 0 conflicts).
// (row>>1)&3 is invariant under row+64 and all fragment row bases, so
// csw/qsw are single per-thread constants. Staging coalescing preserved:
// each 4-lane group covers one contiguous 64B segment, permuted within it.
// MODE 0 epilogue: bias + head_mask; Q -> [nh][s][d] (x log2(e)/8);
//   K -> fragment-major Kf with the LANE-LOCAL-P permutation baked in
//     (key g at C-tile ct = 2*(g>>5)+((g>>2)&1), row i = ((g>>3)&3)*4+(g&3));
//   V -> natural fragment-major Vf. Both key-linear at 64-key granularity.
// MODE 1: fp32 out = acc + bias.
#define GEMM_STAGE(k0_, buf_)                                                    \
  {                                                                              \
    async_ld16(A + (size_t)(rowBase + r0) * Kdim + (k0_) + csw, &As[buf_][f0]);  \
    async_ld16(A + (size_t)(rowBase + r1) * Kdim + (k0_) + csw, &As[buf_][f1]);  \
    async_ld16(Bw + (size_t)(colBase + r0) * Kdim + (k0_) + csw, &Bs[buf_][f0]); \
    async_ld16(Bw + (size_t)(colBase + r1) * Kdim + (k0_) + csw, &Bs[buf_][f1]); \
  }

template <int MODE>
__global__ __launch_bounds__(256, 2) void gemm_bt_kernel(
    const bf16* __restrict__ A, const bf16* __restrict__ Bw,
    const float* __restrict__ bias, const float* __restrict__ hm,
    bf16* __restrict__ Qp, bf16* __restrict__ Kp, bf16* __restrict__ Vp,
    float* __restrict__ outF, int Ncols, int Kdim, int rowBlkCount) {
  __shared__ bf16 As[2][128 * 32];
  __shared__ bf16 Bs[2][128 * 32];
  const int t = threadIdx.x, lane = t & 63, w = t >> 6;
  const int wr = w >> 1, wc = w & 1;
  const int j = lane & 15, quad = lane >> 4;
  const int rowBlk = blockIdx.x % rowBlkCount;
  const int colBlk = blockIdx.x / rowBlkCount;
  const int rowBase = rowBlk * 128, colBase = colBlk * 128;

  f32x4 acc[4][4];
  const f32x4 z4 = {0.f, 0.f, 0.f, 0.f};
#pragma unroll
  for (int i = 0; i < 4; ++i)
#pragma unroll
    for (int jj = 0; jj < 4; ++jj) acc[i][jj] = z4;

  const int f0 = t * 8;
  const int f1 = f0 + 2048;
  const int r0 = f0 >> 5, r1 = r0 + 64;
  // swizzled global source column: granule (t&3) XOR (row>>1)&3, in elements.
  // Same for f0/f1 rows (r1 = r0+64 -> (r1>>1)&3 == (r0>>1)&3).
  const int csw = (((t & 3) ^ ((r0 >> 1) & 3))) * 8;
  // fragment-read granule XOR: row = (multiple of 4) + j -> (row>>1)&3 = (j>>1)&3
  const int qsw = (quad ^ ((j >> 1) & 3)) * 8;

  GEMM_STAGE(0, 0);
  int buf = 0;
  for (int k0 = 0; k0 < Kdim; k0 += 32) {
    __syncthreads();  // buf staged; all waves done reading buf^1
    if (k0 + 32 < Kdim) GEMM_STAGE(k0 + 32, buf ^ 1);  // overlaps compute below
    bf16x8 af[4], bfr[4];
#pragma unroll
    for (int i = 0; i < 4; ++i)
      af[i] = *(const bf16x8*)&As[buf][(wr * 64 + i * 16 + j) * 32 + qsw];
#pragma unroll
    for (int jj = 0; jj < 4; ++jj)
      bfr[jj] = *(const bf16x8*)&Bs[buf][(wc * 64 + jj * 16 + j) * 32 + qsw];
#pragma unroll
    for (int i = 0; i < 4; ++i)
#pragma unroll
      for (int jj = 0; jj < 4; ++jj)
        acc[i][jj] = __builtin_amdgcn_mfma_f32_16x16x32_bf16(af[i], bfr[jj], acc[i][jj], 0, 0, 0);
    buf ^= 1;
  }

  if (MODE == 0) {
#pragma unroll
    for (int jj = 0; jj < 4; ++jj) {
      int col = colBase + wc * 64 + jj * 16 + j;
      int hh = col / 192;
      int rem = col - hh * 192;
      int mm = rem >> 6;   // wave-uniform (16-col runs never cross a 64 boundary)
      int dd = rem & 63;
      float hmv = hm[hh];
      float bv = bias[col];
      float sc = (mm == 0) ? hmv * 0.18033688011112042f : hmv;  // log2(e)/8 folded into Q
#pragma unroll
      for (int i = 0; i < 4; ++i) {
#pragma unroll
        for (int r = 0; r < 4; ++r) {
          int row = rowBase + wr * 64 + i * 16 + quad * 4 + r;
          int n = row >> 11, ss = row & 2047;
          size_t nh = (size_t)(n * 16 + hh);
          float val = (acc[i][jj][r] + bv) * sc;
          if (mm == 0) {
            Qp[nh * 131072 + ss * 64 + dd] = (bf16)val;
          } else if (mm == 1) {
            // lane-local-P Kf: g = ss&127, T = ss>>7,
            // ct = 2*((g>>5)&3) + ((g>>2)&1), i = ((g>>3)&3)*4 + (g&3)
            size_t idx = nh * 131072 + (size_t)(ss >> 7) * 8192 +
                         (size_t)(2 * ((ss >> 5) & 3) + ((ss >> 2) & 1)) * 1024 +
                         (dd >> 5) * 512 + ((dd >> 3) & 3) * 128 +
                         (((ss >> 3) & 3) * 4 + (ss & 3)) * 8 + (dd & 7);
            Kp[idx] = (bf16)val;
          } else {
            // natural fragment-major V: tile (ss>>7), block (kk=(ss>>5)&3, dt=dd>>4),
            // within block quad=(ss>>3)&3, j=dd&15, elem=ss&7
            size_t idx = nh * 131072 + (size_t)(ss >> 7) * 8192 +
                         (((ss >> 5) & 3) * 4 + (dd >> 4)) * 512 +
                         ((ss >> 3) & 3) * 128 + (dd & 15) * 8 + (ss & 7);
            Vp[idx] = (bf16)val;
          }
        }
      }
    }
  } else {
#pragma unroll
    for (int jj = 0; jj < 4; ++jj) {
      int col = colBase + wc * 64 + jj * 16 + j;
      float bv = bias[col];
#pragma unroll
      for (int i = 0; i < 4; ++i)
#pragma unroll
        for (int r = 0; r < 4; ++r) {
          int row = rowBase + wr * 64 + i * 16 + quad * 4 + r;
          outF[(size_t)row * Ncols + col] = acc[i][jj][r] + bv;
        }
    }
  }
}

// ---------------- Flash attention: swapped QK^T, lane-local P, PIPELINED ----
// (unchanged from the passing rounds 5/6: 2-phase double-buffered staging,
// lane-local in-register P via Kf permutation, explicit-RNE pack, fixed-max
// softmax, fp32 l. LDS 32KB => 4 blocks/CU, grid 1024 fully resident.)
#define FLASH_STAGE(tileIdx, KsBuf, VsBuf)                                  \
  {                                                                         \
    const bf16* kn_ = Kc + (tileIdx) * 4096;                                \
    const bf16* vn_ = Vc + (tileIdx) * 4096;                                \
    _Pragma("unroll")                                                       \
    for (int p = 0; p < 2; ++p) {                                           \
      int c = (p * 256 + t) * 8;                                            \
      async_ld16(kn_ + c, &KsBuf[c]);                                       \
      async_ld16(vn_ + c, &VsBuf[c]);                                       \
    }                                                                       \
  }

#define FLASH_TILE(KsBuf, VsBuf)                                            \
  {                                                                         \
    unsigned pkd[2][4][2];                                                  \
    _Pragma("unroll")                                                       \
    for (int ct = 0; ct < 4; ++ct) {                                        \
      bf16x8 kf0 = *(const bf16x8*)&KsBuf[ct * 1024 + lane * 8];            \
      bf16x8 kf1 = *(const bf16x8*)&KsBuf[ct * 1024 + 512 + lane * 8];      \
      _Pragma("unroll")                                                     \
      for (int rt = 0; rt < 2; ++rt) {                                      \
        f32x4 sv = z4;                                                      \
        sv = __builtin_amdgcn_mfma_f32_16x16x32_bf16(kf0, qf[rt][0], sv, 0, 0, 0); \
        sv = __builtin_amdgcn_mfma_f32_16x16x32_bf16(kf1, qf[rt][1], sv, 0, 0, 0); \
        float p0 = EXP2F(sv[0]), p1 = EXP2F(sv[1]);                         \
        float p2 = EXP2F(sv[2]), p3 = EXP2F(sv[3]);                         \
        lrow[rt] += (p0 + p1) + (p2 + p3);                                  \
        pkd[rt][ct][0] = pack2(p0, p1);                                     \
        pkd[rt][ct][1] = pack2(p2, p3);                                     \
      }                                                                     \
    }                                                                       \
    _Pragma("unroll")                                                       \
    for (int kk = 0; kk < 2; ++kk) {                                        \
      union { uint4x u; bf16x8 h; } pa[2];                                  \
      _Pragma("unroll")                                                     \
      for (int rt = 0; rt < 2; ++rt)                                        \
        pa[rt].u = (uint4x){pkd[rt][2 * kk][0], pkd[rt][2 * kk][1],         \
                            pkd[rt][2 * kk + 1][0], pkd[rt][2 * kk + 1][1]};\
      _Pragma("unroll")                                                     \
      for (int dt = 0; dt < 4; ++dt) {                                      \
        bf16x8 vf = *(const bf16x8*)&VsBuf[(kk * 4 + dt) * 512 + lane * 8]; \
        oacc[0][dt] = __builtin_amdgcn_mfma_f32_16x16x32_bf16(pa[0].h, vf, oacc[0][dt], 0, 0, 0); \
        oacc[1][dt] = __builtin_amdgcn_mfma_f32_16x16x32_bf16(pa[1].h, vf, oacc[1][dt], 0, 0, 0); \
      }                                                                     \
    }                                                                       \
  }

__global__ __launch_bounds__(256, 4) void flash_kernel(const bf16* __restrict__ Qp,
                                                       const bf16* __restrict__ Kf,
                                                       const bf16* __restrict__ Vf,
                                                       float* __restrict__ O0,
                                                       float* __restrict__ O1,
                                                       float* __restrict__ Lp) {
  __shared__ bf16 Ks0[4096];
  __shared__ bf16 Vs0[4096];
  __shared__ bf16 Ks1[4096];
  __shared__ bf16 Vs1[4096];
  const int t = threadIdx.x, lane = t & 63, w = t >> 6;
  const int j = lane & 15, quad = lane >> 4;
  const int g = blockIdx.x & 63;
  const int qt = blockIdx.x >> 6;   // [0,16)
  const int nh = g >> 1, ck = g & 1;
  const int q0 = qt * 128 + w * 32;
  const bf16* Qb = Qp + (size_t)nh * 131072;
  const bf16* Kc = Kf + (size_t)nh * 131072 + ck * 65536;
  const bf16* Vc = Vf + (size_t)nh * 131072 + ck * 65536;

  bf16x8 qf[2][2];
#pragma unroll
  for (int rt = 0; rt < 2; ++rt)
#pragma unroll
    for (int kd = 0; kd < 2; ++kd)
      qf[rt][kd] = *(const bf16x8*)&Qb[(size_t)(q0 + rt * 16 + j) * 64 + kd * 32 + quad * 8];

  float lrow[2] = {0.f, 0.f};
  f32x4 oacc[2][4];
  const f32x4 z4 = {0.f, 0.f, 0.f, 0.f};
#pragma unroll
  for (int rt = 0; rt < 2; ++rt)
#pragma unroll
    for (int dt = 0; dt < 4; ++dt) oacc[rt][dt] = z4;

  // prologue: stage sub-tile 0 into buffer 0 (only this one is unoverlapped)
  FLASH_STAGE(0, Ks0, Vs0);

  for (int it2 = 0; it2 < 8; ++it2) {
    __syncthreads();  // drains buf0 staging; all waves done reading buf1
    FLASH_STAGE(it2 * 2 + 1, Ks1, Vs1);   // overlaps with compute below
    FLASH_TILE(Ks0, Vs0);
    __syncthreads();  // drains buf1 staging; all waves done reading buf0
    if (it2 < 7) FLASH_STAGE(it2 * 2 + 2, Ks0, Vs0);
    FLASH_TILE(Ks1, Vs1);
  }

  // epilogue: unnormalized partial O (fp32) + per-row l
  float* Od = ck ? O1 : O0;
#pragma unroll
  for (int rt = 0; rt < 2; ++rt) {
    // l for q = q0 + rt*16 + j lives split across the 4 quads: fold them
    float l = lrow[rt];
    l += __shfl_xor(l, 16);
    l += __shfl_xor(l, 32);
    if (quad == 0) Lp[ck * 65536 + (size_t)nh * 2048 + q0 + rt * 16 + j] = l;
#pragma unroll
    for (int r = 0; r < 4; ++r) {
      int srow = q0 + rt * 16 + quad * 4 + r;
      size_t row = (size_t)nh * 2048 + srow;
#pragma unroll
      for (int dt = 0; dt < 4; ++dt)
        Od[row * 64 + dt * 16 + j] = oacc[rt][dt][r];
    }
  }
}

// ---------------- merge two KV-chunk partials -> bf16 attn [n][s][h*64+d] ----
// Fixed-max partials: O = (O0 + O1) / (l0 + l1).
__global__ __launch_bounds__(256) void merge_kernel(const float* __restrict__ O0,
                                                    const float* __restrict__ O1,
                                                    const float* __restrict__ Lp,
                                                    bf16* __restrict__ attn) {
  int g = blockIdx.x * 256 + threadIdx.x;  // 65536 rows x 16 groups of 4 dims
  int row = g >> 4;
  int dg = (g & 15) * 4;
  float inv = 1.0f / (Lp[row] + Lp[65536 + row]);
  f32x4 a = *(const f32x4*)(O0 + (size_t)row * 64 + dg);
  f32x4 b = *(const f32x4*)(O1 + (size_t)row * 64 + dg);
  int nh = row >> 11, s = row & 2047;
  int n = nh >> 4, h = nh & 15;
  bf16x4 o;
#pragma unroll
  for (int i = 0; i < 4; ++i) o[i] = (bf16)((a[i] + b[i]) * inv);
  *(bf16x4*)(attn + ((size_t)(n * 2048 + s)) * 1024 + h * 64 + dg) = o;
}

extern "C" void kernel_launch(void* const* d_in, const int* in_sizes, int n_in,
                              void* d_out, int out_size, void* d_ws, size_t ws_size,
                              hipStream_t stream) {
  const float* x = (const float*)d_in[0];
  const float* head_mask = (const float*)d_in[1];
  const float* qkv_w = (const float*)d_in[2];
  const float* qkv_b = (const float*)d_in[3];
  const float* fc_w = (const float*)d_in[4];
  const float* fc_b = (const float*)d_in[5];
  float* out = (float*)d_out;

  char* ws = (char*)d_ws;
  bf16* x_bf    = (bf16*)(ws + 0);                    // 8 MB (later reused as attn)
  bf16* qkvw_bf = (bf16*)(ws + ((size_t)8 << 20));    // 6 MB
  bf16* fcw_bf  = (bf16*)(ws + ((size_t)14 << 20));   // 2 MB
  bf16* Qp      = (bf16*)(ws + ((size_t)16 << 20));   // 8 MB
  bf16* Kf      = (bf16*)(ws + ((size_t)24 << 20));   // 8 MB (fragment-major K, lane-local-P perm)
  bf16* Vf      = (bf16*)(ws + ((size_t)32 << 20));   // 8 MB (fragment-major V, natural order)
  float* O1     = (float*)(ws + ((size_t)40 << 20));  // 16 MB
  float* Lp     = (float*)(ws + ((size_t)56 << 20));  // 512 KB (2 chunks x 65536)
  float* O0     = (float*)d_out;  // 16 MB scratch; overwritten by gemm2 at the end
  bf16* attn = x_bf;              // x_bf dead after gemm1

  cvt3_kernel<<<8192, 256, 0, stream>>>(x, qkv_w, fc_w, x_bf, qkvw_bf, fcw_bf);
  gemm_bt_kernel<0><<<32 * 24, 256, 0, stream>>>(x_bf, qkvw_bf, qkv_b, head_mask,
                                                 Qp, Kf, Vf, nullptr, 3072, 1024, 32);
  flash_kernel<<<1024, 256, 0, stream>>>(Qp, Kf, Vf, O0, O1, Lp);
  merge_kernel<<<4096, 256, 0, stream>>>(O0, O1, Lp, attn);
  gemm_bt_kernel<1><<<32 * 8, 256, 0, stream>>>(attn, fcw_bf, fc_b, nullptr,
                                                nullptr, nullptr, nullptr, out, 1024, 1024, 32);
}

// Round 9
// 191.338 us; speedup vs baseline: 1.1449x; 1.0614x over previous
//
#include <hip/hip_runtime.h>
#include <hip/hip_bf16.h>

typedef __bf16 bf16;
typedef __attribute__((ext_vector_type(8))) __bf16 bf16x8;
typedef __attribute__((ext_vector_type(4))) __bf16 bf16x4;
typedef __attribute__((ext_vector_type(4))) float f32x4;
typedef __attribute__((ext_vector_type(4))) unsigned int uint4x;

#if __has_builtin(__builtin_amdgcn_exp2f)
#define EXP2F(x) __builtin_amdgcn_exp2f(x)
#else
#define EXP2F(x) exp2f(x)
#endif

#define AS1 __attribute__((address_space(1)))
#define AS3 __attribute__((address_space(3)))

static __device__ __forceinline__ void async_ld16(const bf16* g, bf16* l) {
  __builtin_amdgcn_global_load_lds((const AS1 void*)g, (AS3 void*)l, 16, 0, 0);
}

// f32 -> bf16 with EXPLICIT round-to-nearest-even bit arithmetic (proven in
// round 4: cvt_pk-based paths failed at ~9e-3; this passes at 2.4e-3).
// Valid for positive finite inputs (exp2 output); no NaN handling needed.
static __device__ __forceinline__ unsigned bf16rne(float x) {
  unsigned u = __float_as_uint(x);
  return (u + 0x7fffu + ((u >> 16) & 1u)) >> 16;
}
static __device__ __forceinline__ unsigned pack2(float a, float b) {
  return bf16rne(a) | (bf16rne(b) << 16);
}

// ---------------- fused fp32 -> bf16 conversion (x, qkv_w, fc_w) ----------
__global__ void cvt3_kernel(const float* __restrict__ x, const float* __restrict__ qw,
                            const float* __restrict__ fw, bf16* __restrict__ xb,
                            bf16* __restrict__ qwb, bf16* __restrict__ fwb) {
  int b = blockIdx.x;
  const float* src;
  bf16* dst;
  int i;
  if (b < 4096) { src = x; dst = xb; i = b * 256 + threadIdx.x; }
  else if (b < 7168) { src = qw; dst = qwb; i = (b - 4096) * 256 + threadIdx.x; }
  else { src = fw; dst = fwb; i = (b - 7168) * 256 + threadIdx.x; }
  f32x4 v = *(const f32x4*)(src + (size_t)i * 4);
  bf16x4 o;
  o[0] = (bf16)v[0]; o[1] = (bf16)v[1]; o[2] = (bf16)v[2]; o[3] = (bf16)v[3];
  *(bf16x4*)(dst + (size_t)i * 4) = o;
}

// ---------------- BT-GEMM: C[M,N] = A[M,K] @ B[N,K]^T ----------------
// (byte-identical to the passing round 8: 2-phase double-buffer + T2
// pre-swizzled-source XOR swizzle on the fragment reads.)
// MODE 0 epilogue: bias + head_mask; Q -> [nh][s][d] (x log2(e)/8);
//   K -> fragment-major Kf with the LANE-LOCAL-P permutation baked in
//     (key g at C-tile ct = 2*(g>>5)+((g>>2)&1), row i = ((g>>3)&3)*4+(g&3));
//   V -> natural fragment-major Vf. Both key-linear at 64-key granularity.
// MODE 1: fp32 out = acc + bias.
#define GEMM_STAGE(k0_, buf_)                                                    \
  {                                                                              \
    async_ld16(A + (size_t)(rowBase + r0) * Kdim + (k0_) + csw, &As[buf_][f0]);  \
    async_ld16(A + (size_t)(rowBase + r1) * Kdim + (k0_) + csw, &As[buf_][f1]);  \
    async_ld16(Bw + (size_t)(colBase + r0) * Kdim + (k0_) + csw, &Bs[buf_][f0]); \
    async_ld16(Bw + (size_t)(colBase + r1) * Kdim + (k0_) + csw, &Bs[buf_][f1]); \
  }

template <int MODE>
__global__ __launch_bounds__(256, 2) void gemm_bt_kernel(
    const bf16* __restrict__ A, const bf16* __restrict__ Bw,
    const float* __restrict__ bias, const float* __restrict__ hm,
    bf16* __restrict__ Qp, bf16* __restrict__ Kp, bf16* __restrict__ Vp,
    float* __restrict__ outF, int Ncols, int Kdim, int rowBlkCount) {
  __shared__ bf16 As[2][128 * 32];
  __shared__ bf16 Bs[2][128 * 32];
  const int t = threadIdx.x, lane = t & 63, w = t >> 6;
  const int wr = w >> 1, wc = w & 1;
  const int j = lane & 15, quad = lane >> 4;
  const int rowBlk = blockIdx.x % rowBlkCount;
  const int colBlk = blockIdx.x / rowBlkCount;
  const int rowBase = rowBlk * 128, colBase = colBlk * 128;

  f32x4 acc[4][4];
  const f32x4 z4 = {0.f, 0.f, 0.f, 0.f};
#pragma unroll
  for (int i = 0; i < 4; ++i)
#pragma unroll
    for (int jj = 0; jj < 4; ++jj) acc[i][jj] = z4;

  const int f0 = t * 8;
  const int f1 = f0 + 2048;
  const int r0 = f0 >> 5, r1 = r0 + 64;
  const int csw = (((t & 3) ^ ((r0 >> 1) & 3))) * 8;
  const int qsw = (quad ^ ((j >> 1) & 3)) * 8;

  GEMM_STAGE(0, 0);
  int buf = 0;
  for (int k0 = 0; k0 < Kdim; k0 += 32) {
    __syncthreads();  // buf staged; all waves done reading buf^1
    if (k0 + 32 < Kdim) GEMM_STAGE(k0 + 32, buf ^ 1);  // overlaps compute below
    bf16x8 af[4], bfr[4];
#pragma unroll
    for (int i = 0; i < 4; ++i)
      af[i] = *(const bf16x8*)&As[buf][(wr * 64 + i * 16 + j) * 32 + qsw];
#pragma unroll
    for (int jj = 0; jj < 4; ++jj)
      bfr[jj] = *(const bf16x8*)&Bs[buf][(wc * 64 + jj * 16 + j) * 32 + qsw];
#pragma unroll
    for (int i = 0; i < 4; ++i)
#pragma unroll
      for (int jj = 0; jj < 4; ++jj)
        acc[i][jj] = __builtin_amdgcn_mfma_f32_16x16x32_bf16(af[i], bfr[jj], acc[i][jj], 0, 0, 0);
    buf ^= 1;
  }

  if (MODE == 0) {
#pragma unroll
    for (int jj = 0; jj < 4; ++jj) {
      int col = colBase + wc * 64 + jj * 16 + j;
      int hh = col / 192;
      int rem = col - hh * 192;
      int mm = rem >> 6;   // wave-uniform (16-col runs never cross a 64 boundary)
      int dd = rem & 63;
      float hmv = hm[hh];
      float bv = bias[col];
      float sc = (mm == 0) ? hmv * 0.18033688011112042f : hmv;  // log2(e)/8 folded into Q
#pragma unroll
      for (int i = 0; i < 4; ++i) {
#pragma unroll
        for (int r = 0; r < 4; ++r) {
          int row = rowBase + wr * 64 + i * 16 + quad * 4 + r;
          int n = row >> 11, ss = row & 2047;
          size_t nh = (size_t)(n * 16 + hh);
          float val = (acc[i][jj][r] + bv) * sc;
          if (mm == 0) {
            Qp[nh * 131072 + ss * 64 + dd] = (bf16)val;
          } else if (mm == 1) {
            // lane-local-P Kf: g = ss&127, T = ss>>7,
            // ct = 2*((g>>5)&3) + ((g>>2)&1), i = ((g>>3)&3)*4 + (g&3)
            size_t idx = nh * 131072 + (size_t)(ss >> 7) * 8192 +
                         (size_t)(2 * ((ss >> 5) & 3) + ((ss >> 2) & 1)) * 1024 +
                         (dd >> 5) * 512 + ((dd >> 3) & 3) * 128 +
                         (((ss >> 3) & 3) * 4 + (ss & 3)) * 8 + (dd & 7);
            Kp[idx] = (bf16)val;
          } else {
            // natural fragment-major V: tile (ss>>7), block (kk=(ss>>5)&3, dt=dd>>4),
            // within block quad=(ss>>3)&3, j=dd&15, elem=ss&7
            size_t idx = nh * 131072 + (size_t)(ss >> 7) * 8192 +
                         (((ss >> 5) & 3) * 4 + (dd >> 4)) * 512 +
                         ((ss >> 3) & 3) * 128 + (dd & 15) * 8 + (ss & 7);
            Vp[idx] = (bf16)val;
          }
        }
      }
    }
  } else {
#pragma unroll
    for (int jj = 0; jj < 4; ++jj) {
      int col = colBase + wc * 64 + jj * 16 + j;
      float bv = bias[col];
#pragma unroll
      for (int i = 0; i < 4; ++i)
#pragma unroll
        for (int r = 0; r < 4; ++r) {
          int row = rowBase + wr * 64 + i * 16 + quad * 4 + r;
          outF[(size_t)row * Ncols + col] = acc[i][jj][r] + bv;
        }
    }
  }
}

// ---------------- Flash attention: 8-wave block, IN-BLOCK chunk merge -------
// ROUND-9 CHANGE (one structural variable): both KV-chunks of a q-tile live
// in ONE 512-thread block (waves 0-3 = chunk 0, waves 4-7 = chunk 1, each
// with its own 32KB double-buffered staging pipeline; 65KB LDS/block, 2
// blocks/CU = same 16 waves/CU as before). After the K-loop, chunk-1 waves
// dump O-partials (32KB, overlaying the dead K-staging LDS) + l to LDS;
// chunk-0 waves combine (O0+O1)/(l0+l1) in-register and write final bf16
// attn DIRECTLY. This deletes the merge kernel and the O0/O1/Lp round-trip
// (~110 MB of HBM traffic + one launch). Value math is identical to the old
// merge (same fp32 adds, same 1/l, same scalar bf16 cast).
// grid = 512: b = qt*32 + nh (blocks sharing a head are b, b+32 -> same XCD).
// Per-wave compute/staging structure unchanged from passing rounds 5-8.
#define FLASH_STAGE(tileIdx, KsBuf, VsBuf)                                  \
  {                                                                         \
    const bf16* kn_ = Kc + (tileIdx) * 4096;                                \
    const bf16* vn_ = Vc + (tileIdx) * 4096;                                \
    _Pragma("unroll")                                                       \
    for (int p = 0; p < 2; ++p) {                                           \
      int c = (p * 256 + ts) * 8;                                           \
      async_ld16(kn_ + c, &(KsBuf)[c]);                                     \
      async_ld16(vn_ + c, &(VsBuf)[c]);                                     \
    }                                                                       \
  }

#define FLASH_TILE(KsBuf, VsBuf)                                            \
  {                                                                         \
    unsigned pkd[2][4][2];                                                  \
    _Pragma("unroll")                                                       \
    for (int ct = 0; ct < 4; ++ct) {                                        \
      bf16x8 kf0 = *(const bf16x8*)&(KsBuf)[ct * 1024 + lane * 8];          \
      bf16x8 kf1 = *(const bf16x8*)&(KsBuf)[ct * 1024 + 512 + lane * 8];    \
      _Pragma("unroll")                                                     \
      for (int rt = 0; rt < 2; ++rt) {                                      \
        f32x4 sv = z4;                                                      \
        sv = __builtin_amdgcn_mfma_f32_16x16x32_bf16(kf0, qf[rt][0], sv, 0, 0, 0); \
        sv = __builtin_amdgcn_mfma_f32_16x16x32_bf16(kf1, qf[rt][1], sv, 0, 0, 0); \
        float p0 = EXP2F(sv[0]), p1 = EXP2F(sv[1]);                         \
        float p2 = EXP2F(sv[2]), p3 = EXP2F(sv[3]);                         \
        lrow[rt] += (p0 + p1) + (p2 + p3);                                  \
        pkd[rt][ct][0] = pack2(p0, p1);                                     \
        pkd[rt][ct][1] = pack2(p2, p3);                                     \
      }                                                                     \
    }                                                                       \
    _Pragma("unroll")                                                       \
    for (int kk = 0; kk < 2; ++kk) {                                        \
      union { uint4x u; bf16x8 h; } pa[2];                                  \
      _Pragma("unroll")                                                     \
      for (int rt = 0; rt < 2; ++rt)                                        \
        pa[rt].u = (uint4x){pkd[rt][2 * kk][0], pkd[rt][2 * kk][1],         \
                            pkd[rt][2 * kk + 1][0], pkd[rt][2 * kk + 1][1]};\
      _Pragma("unroll")                                                     \
      for (int dt = 0; dt < 4; ++dt) {                                      \
        bf16x8 vf = *(const bf16x8*)&(VsBuf)[(kk * 4 + dt) * 512 + lane * 8]; \
        oacc[0][dt] = __builtin_amdgcn_mfma_f32_16x16x32_bf16(pa[0].h, vf, oacc[0][dt], 0, 0, 0); \
        oacc[1][dt] = __builtin_amdgcn_mfma_f32_16x16x32_bf16(pa[1].h, vf, oacc[1][dt], 0, 0, 0); \
      }                                                                     \
    }                                                                       \
  }

__global__ __launch_bounds__(512, 4) void flash_kernel(const bf16* __restrict__ Qp,
                                                       const bf16* __restrict__ Kf,
                                                       const bf16* __restrict__ Vf,
                                                       bf16* __restrict__ attn) {
  __shared__ bf16 Kst[2][2][4096];   // [chunk][buf][..]  32 KB (Osh overlays)
  __shared__ bf16 Vst[2][2][4096];   // 32 KB
  __shared__ float Lsh[8][32];       // per-wave folded l  1 KB
  const int t = threadIdx.x, lane = t & 63, w = t >> 6;
  const int ts = t & 255;            // thread id within chunk-half
  const int hc = t >> 8;             // chunk (0: waves 0-3, 1: waves 4-7)
  const int j = lane & 15, quad = lane >> 4;
  const int b = blockIdx.x;
  const int qt = b >> 5;             // [0,16)
  const int nh = b & 31;
  const int q0 = qt * 128 + (w & 3) * 32;
  const bf16* Qb = Qp + (size_t)nh * 131072;
  const bf16* Kc = Kf + (size_t)nh * 131072 + hc * 65536;
  const bf16* Vc = Vf + (size_t)nh * 131072 + hc * 65536;

  bf16x8 qf[2][2];
#pragma unroll
  for (int rt = 0; rt < 2; ++rt)
#pragma unroll
    for (int kd = 0; kd < 2; ++kd)
      qf[rt][kd] = *(const bf16x8*)&Qb[(size_t)(q0 + rt * 16 + j) * 64 + kd * 32 + quad * 8];

  float lrow[2] = {0.f, 0.f};
  f32x4 oacc[2][4];
  const f32x4 z4 = {0.f, 0.f, 0.f, 0.f};
#pragma unroll
  for (int rt = 0; rt < 2; ++rt)
#pragma unroll
    for (int dt = 0; dt < 4; ++dt) oacc[rt][dt] = z4;

  // prologue: stage sub-tile 0 into buffer 0 (only this one is unoverlapped)
  FLASH_STAGE(0, Kst[hc][0], Vst[hc][0]);

  for (int it2 = 0; it2 < 8; ++it2) {
    __syncthreads();  // drains buf0 staging; all waves done reading buf1
    FLASH_STAGE(it2 * 2 + 1, Kst[hc][1], Vst[hc][1]);   // overlaps compute
    FLASH_TILE(Kst[hc][0], Vst[hc][0]);
    __syncthreads();  // drains buf1 staging; all waves done reading buf0
    if (it2 < 7) FLASH_STAGE(it2 * 2 + 2, Kst[hc][0], Vst[hc][0]);
    FLASH_TILE(Kst[hc][1], Vst[hc][1]);
  }

  // ---- in-block chunk merge ----
  // fold l across quads: lane (0,j) holds l for q = q0 + rt*16 + j
  float lf[2];
#pragma unroll
  for (int rt = 0; rt < 2; ++rt) {
    float l = lrow[rt];
    l += __shfl_xor(l, 16);
    l += __shfl_xor(l, 32);
    lf[rt] = l;
  }
  __syncthreads();  // all waves done with Kst/Vst -> safe to overlay Osh
  if (quad == 0) {
    Lsh[w][j] = lf[0];
    Lsh[w][16 + j] = lf[1];
  }
  float* Osh = (float*)&Kst[0][0][0];  // 32 KB = 4 waves x 2rt x 4dt x 4r x 64
  if (w >= 4) {
    int wb = w - 4;
#pragma unroll
    for (int rt = 0; rt < 2; ++rt)
#pragma unroll
      for (int dt = 0; dt < 4; ++dt)
#pragma unroll
        for (int r = 0; r < 4; ++r)
          Osh[((((wb * 2 + rt) * 4 + dt) * 4) + r) * 64 + lane] = oacc[rt][dt][r];
  }
  __syncthreads();  // Osh + Lsh visible
  if (w < 4) {
    int n = nh >> 4, h = nh & 15;
    float inv[2][4];
#pragma unroll
    for (int rt = 0; rt < 2; ++rt)
#pragma unroll
      for (int r = 0; r < 4; ++r) {
        int idx = rt * 16 + quad * 4 + r;
        inv[rt][r] = 1.0f / (Lsh[w][idx] + Lsh[w + 4][idx]);
      }
#pragma unroll
    for (int rt = 0; rt < 2; ++rt)
#pragma unroll
      for (int r = 0; r < 4; ++r) {
        int s = q0 + rt * 16 + quad * 4 + r;
        size_t base = ((size_t)(n * 2048 + s)) * 1024 + h * 64;
#pragma unroll
        for (int dt = 0; dt < 4; ++dt) {
          float o = oacc[rt][dt][r] +
                    Osh[((((w * 2 + rt) * 4 + dt) * 4) + r) * 64 + lane];
          attn[base + dt * 16 + j] = (bf16)(o * inv[rt][r]);
        }
      }
  }
}

extern "C" void kernel_launch(void* const* d_in, const int* in_sizes, int n_in,
                              void* d_out, int out_size, void* d_ws, size_t ws_size,
                              hipStream_t stream) {
  const float* x = (const float*)d_in[0];
  const float* head_mask = (const float*)d_in[1];
  const float* qkv_w = (const float*)d_in[2];
  const float* qkv_b = (const float*)d_in[3];
  const float* fc_w = (const float*)d_in[4];
  const float* fc_b = (const float*)d_in[5];
  float* out = (float*)d_out;

  char* ws = (char*)d_ws;
  bf16* x_bf    = (bf16*)(ws + 0);                    // 8 MB (later reused as attn)
  bf16* qkvw_bf = (bf16*)(ws + ((size_t)8 << 20));    // 6 MB
  bf16* fcw_bf  = (bf16*)(ws + ((size_t)14 << 20));   // 2 MB
  bf16* Qp      = (bf16*)(ws + ((size_t)16 << 20));   // 8 MB
  bf16* Kf      = (bf16*)(ws + ((size_t)24 << 20));   // 8 MB (fragment-major K, lane-local-P perm)
  bf16* Vf      = (bf16*)(ws + ((size_t)32 << 20));   // 8 MB (fragment-major V, natural order)
  bf16* attn = x_bf;              // x_bf dead after gemm1

  cvt3_kernel<<<8192, 256, 0, stream>>>(x, qkv_w, fc_w, x_bf, qkvw_bf, fcw_bf);
  gemm_bt_kernel<0><<<32 * 24, 256, 0, stream>>>(x_bf, qkvw_bf, qkv_b, head_mask,
                                                 Qp, Kf, Vf, nullptr, 3072, 1024, 32);
  flash_kernel<<<512, 512, 0, stream>>>(Qp, Kf, Vf, attn);
  gemm_bt_kernel<1><<<32 * 8, 256, 0, stream>>>(attn, fcw_bf, fc_b, nullptr,
                                                nullptr, nullptr, nullptr, out, 1024, 1024, 32);
}